// Round 19
// baseline (277.903 us; speedup 1.0000x reference)
//
#include <hip/hip_runtime.h>
#include <math.h>
#include <float.h>

#define NFEAT 300
#define HID 32
#define NCLS 10
#define GP 16     // padded row stride for layer-2 logits
#define BSZ 128   // nodes per dst-bucket (bucket = dst >> 7)
#define TILE 8192 // edges per k_part tile

__global__ void k_zero_i(int* __restrict__ p, int n) {
    int i = blockIdx.x * 256 + threadIdx.x;
    if (i < n) p[i] = 0;
}

// bucket-level histogram: LDS-privatized, merged via global atomics (782 counters)
__global__ __launch_bounds__(256) void k_bhist(const int* __restrict__ ei, int E, int NB,
                                               int* __restrict__ bcnt) {
    __shared__ int h[1024];
    for (int i = threadIdx.x; i < NB; i += 256) h[i] = 0;
    __syncthreads();
    for (long long i = (long long)blockIdx.x * 256 + threadIdx.x; i < E;
         i += (long long)gridDim.x * 256)
        atomicAdd(&h[ei[E + i] >> 7], 1);
    __syncthreads();
    for (int i = threadIdx.x; i < NB; i += 256) {
        int v = h[i];
        if (v) atomicAdd(&bcnt[i], v);
    }
}

// single-block exclusive scan of bucket counts -> bases (and bcur seed)
__global__ void k_bscan(const int* __restrict__ bcnt, int NB, int E,
                        int* __restrict__ bases, int* __restrict__ bcur) {
    __shared__ int s[1024];
    int tid = threadIdx.x;
    int v = (tid < NB) ? bcnt[tid] : 0;
    s[tid] = v;
    __syncthreads();
    for (int off = 1; off < 1024; off <<= 1) {
        int t = (tid >= off) ? s[tid - off] : 0;
        __syncthreads();
        s[tid] += t;
        __syncthreads();
    }
    if (tid < NB) {
        int ex = s[tid] - v;
        bases[tid] = ex;
        bcur[tid] = ex;
        if (tid == NB - 1) bases[NB] = E;
    }
}

// partition edges into dst-buckets; output packed (dst_local<<17 | src), bucket-contiguous
__global__ __launch_bounds__(256) void k_part(const int* __restrict__ ei, int E, int NB,
                                              int* __restrict__ bcur, int* __restrict__ pp) {
    __shared__ int hist[1024], lbase[1024], gbase[1024], lcur[1024];
    __shared__ int stage[TILE], tgt[TILE];
    int* part = gbase;  // alias: gbase unused until after scan
    int tid = threadIdx.x;
    long long t0 = (long long)blockIdx.x * TILE;
    int nE = (int)(((long long)E - t0 < TILE) ? ((long long)E - t0) : TILE);

    for (int b = tid; b < NB; b += 256) hist[b] = 0;
    __syncthreads();
    for (int i = tid; i < nE; i += 256) {
        int d = ei[E + t0 + i];
        atomicAdd(&hist[d >> 7], 1);
    }
    __syncthreads();
    // exclusive scan hist -> lbase (NB <= 1024), 4 buckets per thread
    int i0 = tid * 4;
    int c0 = (i0 + 0 < NB) ? hist[i0 + 0] : 0;
    int c1 = (i0 + 1 < NB) ? hist[i0 + 1] : 0;
    int c2 = (i0 + 2 < NB) ? hist[i0 + 2] : 0;
    int c3 = (i0 + 3 < NB) ? hist[i0 + 3] : 0;
    int sum = c0 + c1 + c2 + c3;
    part[tid] = sum;
    __syncthreads();
    for (int off = 1; off < 256; off <<= 1) {
        int t = (tid >= off) ? part[tid - off] : 0;
        __syncthreads();
        part[tid] += t;
        __syncthreads();
    }
    int ex = part[tid] - sum;
    if (i0 + 0 < NB) { lbase[i0 + 0] = ex; ex += c0; }
    if (i0 + 1 < NB) { lbase[i0 + 1] = ex; ex += c1; }
    if (i0 + 2 < NB) { lbase[i0 + 2] = ex; ex += c2; }
    if (i0 + 3 < NB) { lbase[i0 + 3] = ex; ex += c3; }
    __syncthreads();  // part (=gbase) consumed; safe to overwrite
    for (int b = tid; b < NB; b += 256) {
        int h = hist[b];
        gbase[b] = h ? atomicAdd(&bcur[b], h) : 0;
        lcur[b] = 0;
    }
    __syncthreads();
    for (int i = tid; i < nE; i += 256) {
        int s = ei[t0 + i];
        int d = ei[E + t0 + i];
        int b = d >> 7;
        int lo = atomicAdd(&lcur[b], 1);
        int slot = lbase[b] + lo;
        stage[slot] = ((d - (b << 7)) << 17) | s;
        tgt[slot] = gbase[b] + lo;
    }
    __syncthreads();
    for (int i = tid; i < nE; i += 256)
        pp[tgt[i]] = stage[i];
}

// per-bucket: count node degrees from pp, scan -> rowptr/dinv, then scatter col
__global__ __launch_bounds__(256) void k_csr(const int* __restrict__ pp,
                                             const int* __restrict__ bases,
                                             int N, int E,
                                             int* __restrict__ rowptr,
                                             float* __restrict__ dinv,
                                             int* __restrict__ col) {
    __shared__ int lc[BSZ], rp[BSZ], sc[BSZ];
    int b = blockIdx.x, tid = threadIdx.x;
    int n0 = b << 7;
    int base = bases[b];
    int cnt = bases[b + 1] - base;
    if (tid < BSZ) lc[tid] = 0;
    __syncthreads();
    for (int i = tid; i < cnt; i += 256)
        atomicAdd(&lc[pp[base + i] >> 17], 1);
    __syncthreads();
    if (tid < BSZ) sc[tid] = lc[tid];
    __syncthreads();
    for (int off = 1; off < BSZ; off <<= 1) {
        int t = (tid < BSZ && tid >= off) ? sc[tid - off] : 0;
        __syncthreads();
        if (tid < BSZ) sc[tid] += t;
        __syncthreads();
    }
    if (tid < BSZ) {
        int node = n0 + tid;
        int ex = base + sc[tid] - lc[tid];  // exclusive prefix
        rp[tid] = ex;
        if (node < N) {
            rowptr[node] = ex;
            dinv[node] = rsqrtf((float)(lc[tid] + 1));  // +1 self-loop
            if (node == N - 1) rowptr[N] = E;
        }
        lc[tid] = 0;
    }
    __syncthreads();
    for (int i = tid; i < cnt; i += 256) {
        int v = pp[base + i];
        int dl = v >> 17;
        int lo = atomicAdd(&lc[dl], 1);
        col[rp[dl] + lo] = v & 0x1FFFF;
    }
}

// h1s[n][k] = dinv[n] * sum_j x[n][j] * W1[j][k]   (pre-scaled by dinv)
// Block = 128 nodes, 4 waves: wave (g = node-half, p = k-16-group), acc[16].
// W1 fully in LDS (38.4 KB, staged once). x in 13 chunks of 24 feats,
// DOUBLE-BUFFERED [128][25] (2-way banks = free): issue next chunk's 3
// float4/thread -> compute current (W = in-order b128 LDS broadcasts, no
// SMEM drains) -> barrier -> write regs -> barrier. Loads stay in flight
// across the whole compute phase.
__global__ __launch_bounds__(256) void k_gemm1(const float* __restrict__ x,
                                               const float* __restrict__ W1,
                                               const float* __restrict__ dinv,
                                               float* __restrict__ h1s, int n) {
    __shared__ float Ws[NFEAT * HID];   // 38.4 KB
    __shared__ float xs[2][128 * 25];   // 2 x 12.5 KB, row stride 25
    int tid = threadIdx.x;
    int lane = tid & 63;
    int w = __builtin_amdgcn_readfirstlane(tid >> 6);
    int g = w & 1;   // node half
    int p = w >> 1;  // k-group: [16p, 16p+16)
    int n0 = blockIdx.x * 128;
    int node = n0 + 64 * g + lane;
    const float4* x4 = reinterpret_cast<const float4*>(x);
    const long long XMAX = (long long)n * 75 - 1;  // clamp for tail-chunk OOB

    // stage W1 (coalesced)
    {
        const float4* w4 = reinterpret_cast<const float4*>(W1);
        float4* s4 = reinterpret_cast<float4*>(Ws);
        for (int i = tid; i < NFEAT * HID / 4; i += 256) s4[i] = w4[i];
    }
    // stage chunk 0: 128 rows x 6 float4 = 768 -> 3 per thread
    {
        int i0 = tid, i1 = tid + 256, i2 = tid + 512;
        int r0 = i0 / 6, f0 = i0 % 6, r1 = i1 / 6, f1 = i1 % 6, r2 = i2 / 6, f2 = i2 % 6;
        float4 a = x4[min((long long)min(n0 + r0, n - 1) * 75 + f0, XMAX)];
        float4 b = x4[min((long long)min(n0 + r1, n - 1) * 75 + f1, XMAX)];
        float4 c = x4[min((long long)min(n0 + r2, n - 1) * 75 + f2, XMAX)];
        float* d0 = &xs[0][r0 * 25 + f0 * 4];
        d0[0] = a.x; d0[1] = a.y; d0[2] = a.z; d0[3] = a.w;
        float* d1 = &xs[0][r1 * 25 + f1 * 4];
        d1[0] = b.x; d1[1] = b.y; d1[2] = b.z; d1[3] = b.w;
        float* d2 = &xs[0][r2 * 25 + f2 * 4];
        d2[0] = c.x; d2[1] = c.y; d2[2] = c.z; d2[3] = c.w;
    }
    __syncthreads();

    float acc[16];
#pragma unroll
    for (int i = 0; i < 16; ++i) acc[i] = 0.f;

    int i0 = tid, i1 = tid + 256, i2 = tid + 512;
    int r0 = i0 / 6, f0 = i0 % 6, r1 = i1 / 6, f1 = i1 % 6, r2 = i2 / 6, f2 = i2 % 6;
    int cur = 0;
    for (int ch = 0; ch < 13; ++ch) {
        bool more = (ch < 12);
        float4 u0, u1, u2;
        if (more) {  // issue next chunk's loads; consumed only after barrier
            int cb = (ch + 1) * 6;
            u0 = x4[min((long long)min(n0 + r0, n - 1) * 75 + cb + f0, XMAX)];
            u1 = x4[min((long long)min(n0 + r1, n - 1) * 75 + cb + f1, XMAX)];
            u2 = x4[min((long long)min(n0 + r2, n - 1) * 75 + cb + f2, XMAX)];
        }
        // compute current chunk from LDS
        int CL = (ch == 12) ? 12 : 24;
        const float* xrow = &xs[cur][(64 * g + lane) * 25];
        const float4* Wq = reinterpret_cast<const float4*>(Ws + (size_t)ch * 24 * HID) + 4 * p;
#pragma unroll 4
        for (int j = 0; j < CL; ++j) {
            float xv = xrow[j];
            float4 w0 = Wq[j * 8 + 0];
            float4 w1 = Wq[j * 8 + 1];
            float4 w2 = Wq[j * 8 + 2];
            float4 w3 = Wq[j * 8 + 3];
            acc[0]  = fmaf(xv, w0.x, acc[0]);  acc[1]  = fmaf(xv, w0.y, acc[1]);
            acc[2]  = fmaf(xv, w0.z, acc[2]);  acc[3]  = fmaf(xv, w0.w, acc[3]);
            acc[4]  = fmaf(xv, w1.x, acc[4]);  acc[5]  = fmaf(xv, w1.y, acc[5]);
            acc[6]  = fmaf(xv, w1.z, acc[6]);  acc[7]  = fmaf(xv, w1.w, acc[7]);
            acc[8]  = fmaf(xv, w2.x, acc[8]);  acc[9]  = fmaf(xv, w2.y, acc[9]);
            acc[10] = fmaf(xv, w2.z, acc[10]); acc[11] = fmaf(xv, w2.w, acc[11]);
            acc[12] = fmaf(xv, w3.x, acc[12]); acc[13] = fmaf(xv, w3.y, acc[13]);
            acc[14] = fmaf(xv, w3.z, acc[14]); acc[15] = fmaf(xv, w3.w, acc[15]);
        }
        __syncthreads();  // readers of xs[cur^1] (prev chunk) are done
        if (more) {
            float* xb = xs[cur ^ 1];
            float* d0 = &xb[r0 * 25 + f0 * 4];
            d0[0] = u0.x; d0[1] = u0.y; d0[2] = u0.z; d0[3] = u0.w;
            float* d1 = &xb[r1 * 25 + f1 * 4];
            d1[0] = u1.x; d1[1] = u1.y; d1[2] = u1.z; d1[3] = u1.w;
            float* d2 = &xb[r2 * 25 + f2 * 4];
            d2[0] = u2.x; d2[1] = u2.y; d2[2] = u2.z; d2[3] = u2.w;
            __syncthreads();  // next chunk visible
            cur ^= 1;
        }
    }
    if (node < n) {
        float dd = dinv[node];
        float4* dst = reinterpret_cast<float4*>(h1s + (size_t)node * HID + 16 * p);
#pragma unroll
        for (int qq = 0; qq < 4; ++qq)
            dst[qq] = make_float4(dd * acc[4 * qq], dd * acc[4 * qq + 1],
                                  dd * acc[4 * qq + 2], dd * acc[4 * qq + 3]);
    }
}

// CSR gather aggregate layer 1 (pre-scaled h1s), fused bias + tanh.
// 8 lanes/node x float4; 4-edge unroll (32 gathers in flight/wave).
__global__ __launch_bounds__(256) void k_agg1(const float* __restrict__ h1s,
                                              const int* __restrict__ rowptr,
                                              const int* __restrict__ col,
                                              const float* __restrict__ dinv,
                                              const float* __restrict__ b1,
                                              float* __restrict__ h2, int n) {
    int node = blockIdx.x * 32 + (threadIdx.x >> 3);
    int l = threadIdx.x & 7;  // float4 lane within node
    if (node >= n) return;
    const float4* h4 = reinterpret_cast<const float4*>(h1s);
    int beg = rowptr[node], end = rowptr[node + 1];
    float4 a0 = h4[(size_t)node * 8 + l];  // self-loop term (pre-scaled)
    float4 a1 = make_float4(0.f, 0.f, 0.f, 0.f);
    float4 a2 = make_float4(0.f, 0.f, 0.f, 0.f);
    float4 a3 = make_float4(0.f, 0.f, 0.f, 0.f);
    int j = beg;
    for (; j + 3 < end; j += 4) {
        int s0 = col[j], s1 = col[j + 1], s2 = col[j + 2], s3 = col[j + 3];
        float4 v0 = h4[(size_t)s0 * 8 + l];
        float4 v1 = h4[(size_t)s1 * 8 + l];
        float4 v2 = h4[(size_t)s2 * 8 + l];
        float4 v3 = h4[(size_t)s3 * 8 + l];
        a0.x += v0.x; a0.y += v0.y; a0.z += v0.z; a0.w += v0.w;
        a1.x += v1.x; a1.y += v1.y; a1.z += v1.z; a1.w += v1.w;
        a2.x += v2.x; a2.y += v2.y; a2.z += v2.z; a2.w += v2.w;
        a3.x += v3.x; a3.y += v3.y; a3.z += v3.z; a3.w += v3.w;
    }
    for (; j < end; ++j) {
        float4 v = h4[(size_t)col[j] * 8 + l];
        a0.x += v.x; a0.y += v.y; a0.z += v.z; a0.w += v.w;
    }
    float dd = dinv[node];
    const float4* b4 = reinterpret_cast<const float4*>(b1);
    float4 bv = b4[l];
    float4 r;
    r.x = tanhf(fmaf(dd, (a0.x + a1.x) + (a2.x + a3.x), bv.x));
    r.y = tanhf(fmaf(dd, (a0.y + a1.y) + (a2.y + a3.y), bv.y));
    r.z = tanhf(fmaf(dd, (a0.z + a1.z) + (a2.z + a3.z), bv.z));
    r.w = tanhf(fmaf(dd, (a0.w + a1.w) + (a2.w + a3.w), bv.w));
    reinterpret_cast<float4*>(h2)[(size_t)node * 8 + l] = r;
}

// gs[n][c] = dinv[n] * sum_k h2[n][k] * W2[k][c], padded row stride GP=16
__global__ __launch_bounds__(256) void k_gemm2(const float* __restrict__ h2,
                                               const float* __restrict__ W2,
                                               const float* __restrict__ dinv,
                                               float* __restrict__ gs, int n) {
    __shared__ float Ws[HID * NCLS];
    for (int i = threadIdx.x; i < HID * NCLS; i += 256) Ws[i] = W2[i];
    __syncthreads();
    int t = blockIdx.x * 256 + threadIdx.x;
    int node = t >> 4, c = t & 15;
    if (node >= n || c >= NCLS) return;
    const float* hr = h2 + (size_t)node * HID;
    float acc = 0.f;
#pragma unroll
    for (int k = 0; k < HID; ++k) acc = fmaf(hr[k], Ws[k * NCLS + c], acc);
    gs[(size_t)node * GP + c] = acc * dinv[node];
}

// CSR gather aggregate layer 2 (pre-scaled gs), fused bias + log-softmax.
// 4 lanes/node x float4 (one gs row = 4 float4s); 2-edge unroll.
__global__ __launch_bounds__(256) void k_agg2(const float* __restrict__ gs,
                                              const int* __restrict__ rowptr,
                                              const int* __restrict__ col,
                                              const float* __restrict__ dinv,
                                              const float* __restrict__ b2,
                                              float* __restrict__ out, int n) {
    int node = blockIdx.x * 64 + (threadIdx.x >> 2);
    int l = threadIdx.x & 3;  // float4 lane: classes 4l..4l+3
    if (node >= n) return;
    const float4* g4 = reinterpret_cast<const float4*>(gs);
    int beg = rowptr[node], end = rowptr[node + 1];
    float4 a0 = g4[(size_t)node * 4 + l];  // self-loop term (pre-scaled)
    float4 a1 = make_float4(0.f, 0.f, 0.f, 0.f);
    int j = beg;
    for (; j + 1 < end; j += 2) {
        int s0 = col[j], s1 = col[j + 1];
        float4 v0 = g4[(size_t)s0 * 4 + l];
        float4 v1 = g4[(size_t)s1 * 4 + l];
        a0.x += v0.x; a0.y += v0.y; a0.z += v0.z; a0.w += v0.w;
        a1.x += v1.x; a1.y += v1.y; a1.z += v1.z; a1.w += v1.w;
    }
    if (j < end) {
        float4 v = g4[(size_t)col[j] * 4 + l];
        a0.x += v.x; a0.y += v.y; a0.z += v.z; a0.w += v.w;
    }
    float dd = dinv[node];
    int c0 = 4 * l;
    float val[4];
    float av[4] = {a0.x + a1.x, a0.y + a1.y, a0.z + a1.z, a0.w + a1.w};
#pragma unroll
    for (int i = 0; i < 4; ++i) {
        int c = c0 + i;
        val[i] = (c < NCLS) ? fmaf(dd, av[i], b2[c]) : -FLT_MAX;
    }
    float m = fmaxf(fmaxf(val[0], val[1]), fmaxf(val[2], val[3]));
    m = fmaxf(m, __shfl_xor(m, 1, 4));
    m = fmaxf(m, __shfl_xor(m, 2, 4));
    float s = 0.f;
#pragma unroll
    for (int i = 0; i < 4; ++i)
        if (c0 + i < NCLS) s += expf(val[i] - m);
    s += __shfl_xor(s, 1, 4);
    s += __shfl_xor(s, 2, 4);
    float ls = m + logf(s);
    float* orow = out + (size_t)node * NCLS;
#pragma unroll
    for (int i = 0; i < 4; ++i)
        if (c0 + i < NCLS) orow[c0 + i] = val[i] - ls;
}

static inline size_t align256(size_t b) { return (b + 255) & ~(size_t)255; }

extern "C" void kernel_launch(void* const* d_in, const int* in_sizes, int n_in,
                              void* d_out, int out_size, void* d_ws, size_t ws_size,
                              hipStream_t stream) {
    const float* x  = (const float*)d_in[0];
    const int*   ei = (const int*)d_in[1];
    const float* W1 = (const float*)d_in[2];
    const float* b1 = (const float*)d_in[3];
    const float* W2 = (const float*)d_in[4];
    const float* b2 = (const float*)d_in[5];
    float* out = (float*)d_out;

    const int N = in_sizes[0] / NFEAT;   // 100000
    const int E = in_sizes[1] / 2;       // 3200000
    const int NB = (N + BSZ - 1) / BSZ;  // 782 dst-buckets

    char* p = (char*)d_ws;
    int* bcnt   = (int*)p;  p += align256(1024 * 4);
    int* bases  = (int*)p;  p += align256(1025 * 4);
    int* bcur   = (int*)p;  p += align256(1024 * 4);
    int* rowptr = (int*)p;  p += align256((size_t)(N + 1) * 4);
    int* pp     = (int*)p;  p += align256((size_t)E * 4);   // packed bucketed edges
    int* col    = (int*)p;  p += align256((size_t)E * 4);
    float* dinv = (float*)p; p += align256((size_t)N * 4);
    float* h1s  = (float*)p; p += align256((size_t)N * HID * 4);
    float* h2   = (float*)p; p += align256((size_t)N * HID * 4);
    float* gs   = h1s;  // N*GP floats; h1s dead after k_agg1

    dim3 B(256);
    int nT = (E + TILE - 1) / TILE;

    k_zero_i<<<4, B, 0, stream>>>(bcnt, 1024);
    k_bhist<<<128, B, 0, stream>>>(ei, E, NB, bcnt);
    k_bscan<<<1, 1024, 0, stream>>>(bcnt, NB, E, bases, bcur);
    k_part<<<nT, B, 0, stream>>>(ei, E, NB, bcur, pp);
    k_csr<<<NB, B, 0, stream>>>(pp, bases, N, E, rowptr, dinv, col);

    k_gemm1<<<(N + 127) / 128, B, 0, stream>>>(x, W1, dinv, h1s, N);
    k_agg1<<<(N + 31) / 32, B, 0, stream>>>(h1s, rowptr, col, dinv, b1, h2, N);
    k_gemm2<<<(N * 16 + 255) / 256, B, 0, stream>>>(h2, W2, dinv, gs, N);
    k_agg2<<<(N + 63) / 64, B, 0, stream>>>(gs, rowptr, col, dinv, b2, out, N);
}

// Round 20
// 264.214 us; speedup vs baseline: 1.0518x; 1.0518x over previous
//
#include <hip/hip_runtime.h>
#include <math.h>
#include <float.h>

#define NFEAT 300
#define HID 32
#define NCLS 10
#define GP 16     // padded row stride for layer-2 logits
#define BSZ 128   // nodes per dst-bucket (bucket = dst >> 7)
#define TILE 8192 // edges per k_part tile
#define XS 264    // xs row stride (floats): 1056 B = 66*16 (b128-aligned rows)

__global__ void k_zero_i(int* __restrict__ p, int n) {
    int i = blockIdx.x * 256 + threadIdx.x;
    if (i < n) p[i] = 0;
}

// bucket-level histogram: LDS-privatized, merged via global atomics (782 counters)
__global__ __launch_bounds__(256) void k_bhist(const int* __restrict__ ei, int E, int NB,
                                               int* __restrict__ bcnt) {
    __shared__ int h[1024];
    for (int i = threadIdx.x; i < NB; i += 256) h[i] = 0;
    __syncthreads();
    for (long long i = (long long)blockIdx.x * 256 + threadIdx.x; i < E;
         i += (long long)gridDim.x * 256)
        atomicAdd(&h[ei[E + i] >> 7], 1);
    __syncthreads();
    for (int i = threadIdx.x; i < NB; i += 256) {
        int v = h[i];
        if (v) atomicAdd(&bcnt[i], v);
    }
}

// single-block exclusive scan of bucket counts -> bases (and bcur seed)
__global__ void k_bscan(const int* __restrict__ bcnt, int NB, int E,
                        int* __restrict__ bases, int* __restrict__ bcur) {
    __shared__ int s[1024];
    int tid = threadIdx.x;
    int v = (tid < NB) ? bcnt[tid] : 0;
    s[tid] = v;
    __syncthreads();
    for (int off = 1; off < 1024; off <<= 1) {
        int t = (tid >= off) ? s[tid - off] : 0;
        __syncthreads();
        s[tid] += t;
        __syncthreads();
    }
    if (tid < NB) {
        int ex = s[tid] - v;
        bases[tid] = ex;
        bcur[tid] = ex;
        if (tid == NB - 1) bases[NB] = E;
    }
}

// partition edges into dst-buckets; output packed (dst_local<<17 | src), bucket-contiguous
__global__ __launch_bounds__(256) void k_part(const int* __restrict__ ei, int E, int NB,
                                              int* __restrict__ bcur, int* __restrict__ pp) {
    __shared__ int hist[1024], lbase[1024], gbase[1024], lcur[1024];
    __shared__ int stage[TILE], tgt[TILE];
    int* part = gbase;  // alias: gbase unused until after scan
    int tid = threadIdx.x;
    long long t0 = (long long)blockIdx.x * TILE;
    int nE = (int)(((long long)E - t0 < TILE) ? ((long long)E - t0) : TILE);

    for (int b = tid; b < NB; b += 256) hist[b] = 0;
    __syncthreads();
    for (int i = tid; i < nE; i += 256) {
        int d = ei[E + t0 + i];
        atomicAdd(&hist[d >> 7], 1);
    }
    __syncthreads();
    // exclusive scan hist -> lbase (NB <= 1024), 4 buckets per thread
    int i0 = tid * 4;
    int c0 = (i0 + 0 < NB) ? hist[i0 + 0] : 0;
    int c1 = (i0 + 1 < NB) ? hist[i0 + 1] : 0;
    int c2 = (i0 + 2 < NB) ? hist[i0 + 2] : 0;
    int c3 = (i0 + 3 < NB) ? hist[i0 + 3] : 0;
    int sum = c0 + c1 + c2 + c3;
    part[tid] = sum;
    __syncthreads();
    for (int off = 1; off < 256; off <<= 1) {
        int t = (tid >= off) ? part[tid - off] : 0;
        __syncthreads();
        part[tid] += t;
        __syncthreads();
    }
    int ex = part[tid] - sum;
    if (i0 + 0 < NB) { lbase[i0 + 0] = ex; ex += c0; }
    if (i0 + 1 < NB) { lbase[i0 + 1] = ex; ex += c1; }
    if (i0 + 2 < NB) { lbase[i0 + 2] = ex; ex += c2; }
    if (i0 + 3 < NB) { lbase[i0 + 3] = ex; ex += c3; }
    __syncthreads();  // part (=gbase) consumed; safe to overwrite
    for (int b = tid; b < NB; b += 256) {
        int h = hist[b];
        gbase[b] = h ? atomicAdd(&bcur[b], h) : 0;
        lcur[b] = 0;
    }
    __syncthreads();
    for (int i = tid; i < nE; i += 256) {
        int s = ei[t0 + i];
        int d = ei[E + t0 + i];
        int b = d >> 7;
        int lo = atomicAdd(&lcur[b], 1);
        int slot = lbase[b] + lo;
        stage[slot] = ((d - (b << 7)) << 17) | s;
        tgt[slot] = gbase[b] + lo;
    }
    __syncthreads();
    for (int i = tid; i < nE; i += 256)
        pp[tgt[i]] = stage[i];
}

// per-bucket: count node degrees from pp, scan -> rowptr/dinv, then scatter col
__global__ __launch_bounds__(256) void k_csr(const int* __restrict__ pp,
                                             const int* __restrict__ bases,
                                             int N, int E,
                                             int* __restrict__ rowptr,
                                             float* __restrict__ dinv,
                                             int* __restrict__ col) {
    __shared__ int lc[BSZ], rp[BSZ], sc[BSZ];
    int b = blockIdx.x, tid = threadIdx.x;
    int n0 = b << 7;
    int base = bases[b];
    int cnt = bases[b + 1] - base;
    if (tid < BSZ) lc[tid] = 0;
    __syncthreads();
    for (int i = tid; i < cnt; i += 256)
        atomicAdd(&lc[pp[base + i] >> 17], 1);
    __syncthreads();
    if (tid < BSZ) sc[tid] = lc[tid];
    __syncthreads();
    for (int off = 1; off < BSZ; off <<= 1) {
        int t = (tid < BSZ && tid >= off) ? sc[tid - off] : 0;
        __syncthreads();
        if (tid < BSZ) sc[tid] += t;
        __syncthreads();
    }
    if (tid < BSZ) {
        int node = n0 + tid;
        int ex = base + sc[tid] - lc[tid];  // exclusive prefix
        rp[tid] = ex;
        if (node < N) {
            rowptr[node] = ex;
            dinv[node] = rsqrtf((float)(lc[tid] + 1));  // +1 self-loop
            if (node == N - 1) rowptr[N] = E;
        }
        lc[tid] = 0;
    }
    __syncthreads();
    for (int i = tid; i < cnt; i += 256) {
        int v = pp[base + i];
        int dl = v >> 17;
        int lo = atomicAdd(&lc[dl], 1);
        col[rp[dl] + lo] = v & 0x1FFFF;
    }
}

// h1s[n][k] = dinv[n] * sum_j x[n][j] * W1[j][k]   (pre-scaled by dinv)
// Block = 256 nodes, 4 waves = 4 k-octets; EACH LANE OWNS 4 NODES (acc[4][8]).
// x staged FEATURE-MAJOR xs[24][XS]: per j, ONE ds_read_b128 loads 4 nodes'
// x[j] (lanes contiguous, conflict-free). W chunk (3 KB) staged per chunk,
// read as 2 b128 broadcasts per j. DS:FMA-instr ratio = 3:32 (was 5:16).
// Reg-staged pipeline: write -> barrier -> issue next -> compute.
__global__ __launch_bounds__(256) void k_gemm1(const float* __restrict__ x,
                                               const float* __restrict__ W1,
                                               const float* __restrict__ dinv,
                                               float* __restrict__ h1s, int n) {
    __shared__ float xs[2][24 * XS];   // 2 x 24.75 KB
    __shared__ float Wc[2][24 * HID];  // 2 x 3 KB
    const int tid = threadIdx.x;
    const int lane = tid & 63;
    const int w = __builtin_amdgcn_readfirstlane(tid >> 6);  // k-octet
    const int n0 = blockIdx.x * 256;
    const float4* x4 = reinterpret_cast<const float4*>(x);
    const float4* w4 = reinterpret_cast<const float4*>(W1);

    float acc[32];
#pragma unroll
    for (int i = 0; i < 32; ++i) acc[i] = 0.f;

    float4 u[6];
    float4 wreg;
    // prologue: load chunk 0 (nf4=6) + its W block into regs
#pragma unroll
    for (int m = 0; m < 6; ++m) {
        int idx = m * 256 + tid, r = idx / 6, fq = idx % 6;
        u[m] = x4[(size_t)min(n0 + r, n - 1) * 75 + fq];
    }
    if (tid < 192) wreg = w4[tid];

    int cur = 0;
    for (int ch = 0; ch < 13; ++ch) {
        const int CL = (ch == 12) ? 12 : 24;
        // WRITE staged regs into LDS buf `cur` (vmcnt waits here)
        if (CL == 24) {
#pragma unroll
            for (int m = 0; m < 6; ++m) {
                int idx = m * 256 + tid, r = idx / 6, fq = idx % 6;
                float* d = &xs[cur][(fq * 4) * XS + r];
                d[0] = u[m].x; d[XS] = u[m].y; d[2 * XS] = u[m].z; d[3 * XS] = u[m].w;
            }
            if (tid < 192) reinterpret_cast<float4*>(Wc[cur])[tid] = wreg;
        } else {
#pragma unroll
            for (int m = 0; m < 3; ++m) {
                int idx = m * 256 + tid, r = idx / 3, fq = idx % 3;
                float* d = &xs[cur][(fq * 4) * XS + r];
                d[0] = u[m].x; d[XS] = u[m].y; d[2 * XS] = u[m].z; d[3 * XS] = u[m].w;
            }
            if (tid < 96) reinterpret_cast<float4*>(Wc[cur])[tid] = wreg;
        }
        __syncthreads();
        // ISSUE next chunk's global loads (in flight across compute)
        if (ch < 12) {
            int nch = ch + 1;
            if (nch < 12) {
#pragma unroll
                for (int m = 0; m < 6; ++m) {
                    int idx = m * 256 + tid, r = idx / 6, fq = idx % 6;
                    u[m] = x4[(size_t)min(n0 + r, n - 1) * 75 + nch * 6 + fq];
                }
                if (tid < 192) wreg = w4[nch * 192 + tid];
            } else {  // tail chunk: 12 feats = 3 f4/row
#pragma unroll
                for (int m = 0; m < 3; ++m) {
                    int idx = m * 256 + tid, r = idx / 3, fq = idx % 3;
                    u[m] = x4[(size_t)min(n0 + r, n - 1) * 75 + 72 + fq];
                }
                if (tid < 96) wreg = w4[12 * 192 + tid];
            }
        }
        // COMPUTE chunk ch from LDS
        const float* xr = &xs[cur][4 * lane];
        const float* wr = &Wc[cur][8 * w];
#pragma unroll 4
        for (int j = 0; j < CL; ++j) {
            float4 xv = *reinterpret_cast<const float4*>(xr + j * XS);
            float4 w0 = *reinterpret_cast<const float4*>(wr + j * HID);
            float4 w1 = *reinterpret_cast<const float4*>(wr + j * HID + 4);
            float xn[4] = {xv.x, xv.y, xv.z, xv.w};
            float wk[8] = {w0.x, w0.y, w0.z, w0.w, w1.x, w1.y, w1.z, w1.w};
#pragma unroll
            for (int nn = 0; nn < 4; ++nn)
#pragma unroll
                for (int kk = 0; kk < 8; ++kk)
                    acc[nn * 8 + kk] = fmaf(xn[nn], wk[kk], acc[nn * 8 + kk]);
        }
        cur ^= 1;
    }
    // epilogue: scale by dinv, store 8 k-outputs for each of the 4 nodes
    float4 dv = reinterpret_cast<const float4*>(dinv + n0)[lane];
    float dvv[4] = {dv.x, dv.y, dv.z, dv.w};
#pragma unroll
    for (int nn = 0; nn < 4; ++nn) {
        int node = n0 + 4 * lane + nn;
        if (node < n) {
            float dd = dvv[nn];
            float4* dst = reinterpret_cast<float4*>(h1s + (size_t)node * HID + 8 * w);
            dst[0] = make_float4(dd * acc[nn * 8 + 0], dd * acc[nn * 8 + 1],
                                 dd * acc[nn * 8 + 2], dd * acc[nn * 8 + 3]);
            dst[1] = make_float4(dd * acc[nn * 8 + 4], dd * acc[nn * 8 + 5],
                                 dd * acc[nn * 8 + 6], dd * acc[nn * 8 + 7]);
        }
    }
}

// CSR gather aggregate layer 1 (pre-scaled h1s), fused bias + tanh.
// 8 lanes/node x float4; 4-edge unroll (32 gathers in flight/wave).
__global__ __launch_bounds__(256) void k_agg1(const float* __restrict__ h1s,
                                              const int* __restrict__ rowptr,
                                              const int* __restrict__ col,
                                              const float* __restrict__ dinv,
                                              const float* __restrict__ b1,
                                              float* __restrict__ h2, int n) {
    int node = blockIdx.x * 32 + (threadIdx.x >> 3);
    int l = threadIdx.x & 7;  // float4 lane within node
    if (node >= n) return;
    const float4* h4 = reinterpret_cast<const float4*>(h1s);
    int beg = rowptr[node], end = rowptr[node + 1];
    float4 a0 = h4[(size_t)node * 8 + l];  // self-loop term (pre-scaled)
    float4 a1 = make_float4(0.f, 0.f, 0.f, 0.f);
    float4 a2 = make_float4(0.f, 0.f, 0.f, 0.f);
    float4 a3 = make_float4(0.f, 0.f, 0.f, 0.f);
    int j = beg;
    for (; j + 3 < end; j += 4) {
        int s0 = col[j], s1 = col[j + 1], s2 = col[j + 2], s3 = col[j + 3];
        float4 v0 = h4[(size_t)s0 * 8 + l];
        float4 v1 = h4[(size_t)s1 * 8 + l];
        float4 v2 = h4[(size_t)s2 * 8 + l];
        float4 v3 = h4[(size_t)s3 * 8 + l];
        a0.x += v0.x; a0.y += v0.y; a0.z += v0.z; a0.w += v0.w;
        a1.x += v1.x; a1.y += v1.y; a1.z += v1.z; a1.w += v1.w;
        a2.x += v2.x; a2.y += v2.y; a2.z += v2.z; a2.w += v2.w;
        a3.x += v3.x; a3.y += v3.y; a3.z += v3.z; a3.w += v3.w;
    }
    for (; j < end; ++j) {
        float4 v = h4[(size_t)col[j] * 8 + l];
        a0.x += v.x; a0.y += v.y; a0.z += v.z; a0.w += v.w;
    }
    float dd = dinv[node];
    const float4* b4 = reinterpret_cast<const float4*>(b1);
    float4 bv = b4[l];
    float4 r;
    r.x = tanhf(fmaf(dd, (a0.x + a1.x) + (a2.x + a3.x), bv.x));
    r.y = tanhf(fmaf(dd, (a0.y + a1.y) + (a2.y + a3.y), bv.y));
    r.z = tanhf(fmaf(dd, (a0.z + a1.z) + (a2.z + a3.z), bv.z));
    r.w = tanhf(fmaf(dd, (a0.w + a1.w) + (a2.w + a3.w), bv.w));
    reinterpret_cast<float4*>(h2)[(size_t)node * 8 + l] = r;
}

// gs[n][c] = dinv[n] * sum_k h2[n][k] * W2[k][c], padded row stride GP=16
__global__ __launch_bounds__(256) void k_gemm2(const float* __restrict__ h2,
                                               const float* __restrict__ W2,
                                               const float* __restrict__ dinv,
                                               float* __restrict__ gs, int n) {
    __shared__ float Ws[HID * NCLS];
    for (int i = threadIdx.x; i < HID * NCLS; i += 256) Ws[i] = W2[i];
    __syncthreads();
    int t = blockIdx.x * 256 + threadIdx.x;
    int node = t >> 4, c = t & 15;
    if (node >= n || c >= NCLS) return;
    const float* hr = h2 + (size_t)node * HID;
    float acc = 0.f;
#pragma unroll
    for (int k = 0; k < HID; ++k) acc = fmaf(hr[k], Ws[k * NCLS + c], acc);
    gs[(size_t)node * GP + c] = acc * dinv[node];
}

// CSR gather aggregate layer 2 (pre-scaled gs), fused bias + log-softmax.
// 4 lanes/node x float4 (one gs row = 4 float4s); 2-edge unroll.
__global__ __launch_bounds__(256) void k_agg2(const float* __restrict__ gs,
                                              const int* __restrict__ rowptr,
                                              const int* __restrict__ col,
                                              const float* __restrict__ dinv,
                                              const float* __restrict__ b2,
                                              float* __restrict__ out, int n) {
    int node = blockIdx.x * 64 + (threadIdx.x >> 2);
    int l = threadIdx.x & 3;  // float4 lane: classes 4l..4l+3
    if (node >= n) return;
    const float4* g4 = reinterpret_cast<const float4*>(gs);
    int beg = rowptr[node], end = rowptr[node + 1];
    float4 a0 = g4[(size_t)node * 4 + l];  // self-loop term (pre-scaled)
    float4 a1 = make_float4(0.f, 0.f, 0.f, 0.f);
    int j = beg;
    for (; j + 1 < end; j += 2) {
        int s0 = col[j], s1 = col[j + 1];
        float4 v0 = g4[(size_t)s0 * 4 + l];
        float4 v1 = g4[(size_t)s1 * 4 + l];
        a0.x += v0.x; a0.y += v0.y; a0.z += v0.z; a0.w += v0.w;
        a1.x += v1.x; a1.y += v1.y; a1.z += v1.z; a1.w += v1.w;
    }
    if (j < end) {
        float4 v = g4[(size_t)col[j] * 4 + l];
        a0.x += v.x; a0.y += v.y; a0.z += v.z; a0.w += v.w;
    }
    float dd = dinv[node];
    int c0 = 4 * l;
    float val[4];
    float av[4] = {a0.x + a1.x, a0.y + a1.y, a0.z + a1.z, a0.w + a1.w};
#pragma unroll
    for (int i = 0; i < 4; ++i) {
        int c = c0 + i;
        val[i] = (c < NCLS) ? fmaf(dd, av[i], b2[c]) : -FLT_MAX;
    }
    float m = fmaxf(fmaxf(val[0], val[1]), fmaxf(val[2], val[3]));
    m = fmaxf(m, __shfl_xor(m, 1, 4));
    m = fmaxf(m, __shfl_xor(m, 2, 4));
    float s = 0.f;
#pragma unroll
    for (int i = 0; i < 4; ++i)
        if (c0 + i < NCLS) s += expf(val[i] - m);
    s += __shfl_xor(s, 1, 4);
    s += __shfl_xor(s, 2, 4);
    float ls = m + logf(s);
    float* orow = out + (size_t)node * NCLS;
#pragma unroll
    for (int i = 0; i < 4; ++i)
        if (c0 + i < NCLS) orow[c0 + i] = val[i] - ls;
}

static inline size_t align256(size_t b) { return (b + 255) & ~(size_t)255; }

extern "C" void kernel_launch(void* const* d_in, const int* in_sizes, int n_in,
                              void* d_out, int out_size, void* d_ws, size_t ws_size,
                              hipStream_t stream) {
    const float* x  = (const float*)d_in[0];
    const int*   ei = (const int*)d_in[1];
    const float* W1 = (const float*)d_in[2];
    const float* b1 = (const float*)d_in[3];
    const float* W2 = (const float*)d_in[4];
    const float* b2 = (const float*)d_in[5];
    float* out = (float*)d_out;

    const int N = in_sizes[0] / NFEAT;   // 100000
    const int E = in_sizes[1] / 2;       // 3200000
    const int NB = (N + BSZ - 1) / BSZ;  // 782 dst-buckets

    char* p = (char*)d_ws;
    int* bcnt   = (int*)p;  p += align256(1024 * 4);
    int* bases  = (int*)p;  p += align256(1025 * 4);
    int* bcur   = (int*)p;  p += align256(1024 * 4);
    int* rowptr = (int*)p;  p += align256((size_t)(N + 1) * 4);
    int* pp     = (int*)p;  p += align256((size_t)E * 4);   // packed bucketed edges
    int* col    = (int*)p;  p += align256((size_t)E * 4);
    float* dinv = (float*)p; p += align256((size_t)N * 4);
    float* h1s  = (float*)p; p += align256((size_t)N * HID * 4);
    float* h2   = (float*)p; p += align256((size_t)N * HID * 4);
    float* gs   = h1s;  // N*GP floats; h1s dead after k_agg1

    dim3 B(256);
    int nT = (E + TILE - 1) / TILE;

    k_zero_i<<<4, B, 0, stream>>>(bcnt, 1024);
    k_bhist<<<128, B, 0, stream>>>(ei, E, NB, bcnt);
    k_bscan<<<1, 1024, 0, stream>>>(bcnt, NB, E, bases, bcur);
    k_part<<<nT, B, 0, stream>>>(ei, E, NB, bcur, pp);
    k_csr<<<NB, B, 0, stream>>>(pp, bases, N, E, rowptr, dinv, col);

    k_gemm1<<<(N + 255) / 256, B, 0, stream>>>(x, W1, dinv, h1s, N);
    k_agg1<<<(N + 31) / 32, B, 0, stream>>>(h1s, rowptr, col, dinv, b1, h2, N);
    k_gemm2<<<(N * 16 + 255) / 256, B, 0, stream>>>(h2, W2, dinv, gs, N);
    k_agg2<<<(N + 63) / 64, B, 0, stream>>>(gs, rowptr, col, dinv, b2, out, N);
}

// Round 21
// 237.517 us; speedup vs baseline: 1.1700x; 1.1124x over previous
//
#include <hip/hip_runtime.h>
#include <math.h>
#include <float.h>

#define NFEAT 300
#define HID 32
#define NCLS 10
#define GP 16     // padded row stride (bf16) for layer-2 logits
#define BSZ 128   // nodes per dst-bucket (bucket = dst >> 7)
#define TILE 8192 // edges per k_part tile
#define XS 264    // xs row stride (floats) in gemm1

typedef unsigned int uint;

__device__ __forceinline__ unsigned short f2bf(float f) {  // RNE float->bf16
    uint u = __float_as_uint(f);
    u += 0x7FFFu + ((u >> 16) & 1u);
    return (unsigned short)(u >> 16);
}
__device__ __forceinline__ uint pack2(float a, float b) {
    return (uint)f2bf(a) | ((uint)f2bf(b) << 16);
}
__device__ __forceinline__ float4 cvt4(uint2 v) {  // 4 bf16 -> 4 f32
    return make_float4(__uint_as_float(v.x << 16),
                       __uint_as_float(v.x & 0xFFFF0000u),
                       __uint_as_float(v.y << 16),
                       __uint_as_float(v.y & 0xFFFF0000u));
}

__global__ void k_zero_i(int* __restrict__ p, int n) {
    int i = blockIdx.x * 256 + threadIdx.x;
    if (i < n) p[i] = 0;
}

// bucket-level histogram: LDS-privatized, merged via global atomics (782 counters)
__global__ __launch_bounds__(256) void k_bhist(const int* __restrict__ ei, int E, int NB,
                                               int* __restrict__ bcnt) {
    __shared__ int h[1024];
    for (int i = threadIdx.x; i < NB; i += 256) h[i] = 0;
    __syncthreads();
    for (long long i = (long long)blockIdx.x * 256 + threadIdx.x; i < E;
         i += (long long)gridDim.x * 256)
        atomicAdd(&h[ei[E + i] >> 7], 1);
    __syncthreads();
    for (int i = threadIdx.x; i < NB; i += 256) {
        int v = h[i];
        if (v) atomicAdd(&bcnt[i], v);
    }
}

// single-block exclusive scan of bucket counts -> bases (and bcur seed)
__global__ void k_bscan(const int* __restrict__ bcnt, int NB, int E,
                        int* __restrict__ bases, int* __restrict__ bcur) {
    __shared__ int s[1024];
    int tid = threadIdx.x;
    int v = (tid < NB) ? bcnt[tid] : 0;
    s[tid] = v;
    __syncthreads();
    for (int off = 1; off < 1024; off <<= 1) {
        int t = (tid >= off) ? s[tid - off] : 0;
        __syncthreads();
        s[tid] += t;
        __syncthreads();
    }
    if (tid < NB) {
        int ex = s[tid] - v;
        bases[tid] = ex;
        bcur[tid] = ex;
        if (tid == NB - 1) bases[NB] = E;
    }
}

// partition edges into dst-buckets; output packed (dst_local<<17 | src), bucket-contiguous
__global__ __launch_bounds__(256) void k_part(const int* __restrict__ ei, int E, int NB,
                                              int* __restrict__ bcur, int* __restrict__ pp) {
    __shared__ int hist[1024], lbase[1024], gbase[1024], lcur[1024];
    __shared__ int stage[TILE], tgt[TILE];
    int* part = gbase;  // alias: gbase unused until after scan
    int tid = threadIdx.x;
    long long t0 = (long long)blockIdx.x * TILE;
    int nE = (int)(((long long)E - t0 < TILE) ? ((long long)E - t0) : TILE);

    for (int b = tid; b < NB; b += 256) hist[b] = 0;
    __syncthreads();
    for (int i = tid; i < nE; i += 256) {
        int d = ei[E + t0 + i];
        atomicAdd(&hist[d >> 7], 1);
    }
    __syncthreads();
    int i0 = tid * 4;
    int c0 = (i0 + 0 < NB) ? hist[i0 + 0] : 0;
    int c1 = (i0 + 1 < NB) ? hist[i0 + 1] : 0;
    int c2 = (i0 + 2 < NB) ? hist[i0 + 2] : 0;
    int c3 = (i0 + 3 < NB) ? hist[i0 + 3] : 0;
    int sum = c0 + c1 + c2 + c3;
    part[tid] = sum;
    __syncthreads();
    for (int off = 1; off < 256; off <<= 1) {
        int t = (tid >= off) ? part[tid - off] : 0;
        __syncthreads();
        part[tid] += t;
        __syncthreads();
    }
    int ex = part[tid] - sum;
    if (i0 + 0 < NB) { lbase[i0 + 0] = ex; ex += c0; }
    if (i0 + 1 < NB) { lbase[i0 + 1] = ex; ex += c1; }
    if (i0 + 2 < NB) { lbase[i0 + 2] = ex; ex += c2; }
    if (i0 + 3 < NB) { lbase[i0 + 3] = ex; ex += c3; }
    __syncthreads();
    for (int b = tid; b < NB; b += 256) {
        int h = hist[b];
        gbase[b] = h ? atomicAdd(&bcur[b], h) : 0;
        lcur[b] = 0;
    }
    __syncthreads();
    for (int i = tid; i < nE; i += 256) {
        int s = ei[t0 + i];
        int d = ei[E + t0 + i];
        int b = d >> 7;
        int lo = atomicAdd(&lcur[b], 1);
        int slot = lbase[b] + lo;
        stage[slot] = ((d - (b << 7)) << 17) | s;
        tgt[slot] = gbase[b] + lo;
    }
    __syncthreads();
    for (int i = tid; i < nE; i += 256)
        pp[tgt[i]] = stage[i];
}

// per-bucket: count node degrees from pp, scan -> rowptr/dinv, then scatter col
__global__ __launch_bounds__(256) void k_csr(const int* __restrict__ pp,
                                             const int* __restrict__ bases,
                                             int N, int E,
                                             int* __restrict__ rowptr,
                                             float* __restrict__ dinv,
                                             int* __restrict__ col) {
    __shared__ int lc[BSZ], rp[BSZ], sc[BSZ];
    int b = blockIdx.x, tid = threadIdx.x;
    int n0 = b << 7;
    int base = bases[b];
    int cnt = bases[b + 1] - base;
    if (tid < BSZ) lc[tid] = 0;
    __syncthreads();
    for (int i = tid; i < cnt; i += 256)
        atomicAdd(&lc[pp[base + i] >> 17], 1);
    __syncthreads();
    if (tid < BSZ) sc[tid] = lc[tid];
    __syncthreads();
    for (int off = 1; off < BSZ; off <<= 1) {
        int t = (tid < BSZ && tid >= off) ? sc[tid - off] : 0;
        __syncthreads();
        if (tid < BSZ) sc[tid] += t;
        __syncthreads();
    }
    if (tid < BSZ) {
        int node = n0 + tid;
        int ex = base + sc[tid] - lc[tid];
        rp[tid] = ex;
        if (node < N) {
            rowptr[node] = ex;
            dinv[node] = rsqrtf((float)(lc[tid] + 1));
            if (node == N - 1) rowptr[N] = E;
        }
        lc[tid] = 0;
    }
    __syncthreads();
    for (int i = tid; i < cnt; i += 256) {
        int v = pp[base + i];
        int dl = v >> 17;
        int lo = atomicAdd(&lc[dl], 1);
        col[rp[dl] + lo] = v & 0x1FFFF;
    }
}

// h1s[n][k] = bf16( dinv[n] * sum_j x[n][j] * W1[j][k] )
// Block = 256 nodes, 4 waves = 4 k-octets; each lane owns 4 nodes (acc[4][8]).
// x staged feature-major xs[24][XS]; W chunk staged; reg-staged pipeline.
__global__ __launch_bounds__(256) void k_gemm1(const float* __restrict__ x,
                                               const float* __restrict__ W1,
                                               const float* __restrict__ dinv,
                                               uint* __restrict__ h1s, int n) {
    __shared__ float xs[2][24 * XS];
    __shared__ float Wc[2][24 * HID];
    const int tid = threadIdx.x;
    const int lane = tid & 63;
    const int w = __builtin_amdgcn_readfirstlane(tid >> 6);  // k-octet
    const int n0 = blockIdx.x * 256;
    const float4* x4 = reinterpret_cast<const float4*>(x);
    const float4* w4 = reinterpret_cast<const float4*>(W1);

    float acc[32];
#pragma unroll
    for (int i = 0; i < 32; ++i) acc[i] = 0.f;

    float4 u[6];
    float4 wreg;
#pragma unroll
    for (int m = 0; m < 6; ++m) {
        int idx = m * 256 + tid, r = idx / 6, fq = idx % 6;
        u[m] = x4[(size_t)min(n0 + r, n - 1) * 75 + fq];
    }
    if (tid < 192) wreg = w4[tid];

    int cur = 0;
    for (int ch = 0; ch < 13; ++ch) {
        const int CL = (ch == 12) ? 12 : 24;
        if (CL == 24) {
#pragma unroll
            for (int m = 0; m < 6; ++m) {
                int idx = m * 256 + tid, r = idx / 6, fq = idx % 6;
                float* d = &xs[cur][(fq * 4) * XS + r];
                d[0] = u[m].x; d[XS] = u[m].y; d[2 * XS] = u[m].z; d[3 * XS] = u[m].w;
            }
            if (tid < 192) reinterpret_cast<float4*>(Wc[cur])[tid] = wreg;
        } else {
#pragma unroll
            for (int m = 0; m < 3; ++m) {
                int idx = m * 256 + tid, r = idx / 3, fq = idx % 3;
                float* d = &xs[cur][(fq * 4) * XS + r];
                d[0] = u[m].x; d[XS] = u[m].y; d[2 * XS] = u[m].z; d[3 * XS] = u[m].w;
            }
            if (tid < 96) reinterpret_cast<float4*>(Wc[cur])[tid] = wreg;
        }
        __syncthreads();
        if (ch < 12) {
            int nch = ch + 1;
            if (nch < 12) {
#pragma unroll
                for (int m = 0; m < 6; ++m) {
                    int idx = m * 256 + tid, r = idx / 6, fq = idx % 6;
                    u[m] = x4[(size_t)min(n0 + r, n - 1) * 75 + nch * 6 + fq];
                }
                if (tid < 192) wreg = w4[nch * 192 + tid];
            } else {
#pragma unroll
                for (int m = 0; m < 3; ++m) {
                    int idx = m * 256 + tid, r = idx / 3, fq = idx % 3;
                    u[m] = x4[(size_t)min(n0 + r, n - 1) * 75 + 72 + fq];
                }
                if (tid < 96) wreg = w4[12 * 192 + tid];
            }
        }
        const float* xr = &xs[cur][4 * lane];
        const float* wr = &Wc[cur][8 * w];
#pragma unroll 4
        for (int j = 0; j < CL; ++j) {
            float4 xv = *reinterpret_cast<const float4*>(xr + j * XS);
            float4 w0 = *reinterpret_cast<const float4*>(wr + j * HID);
            float4 w1 = *reinterpret_cast<const float4*>(wr + j * HID + 4);
            float xn[4] = {xv.x, xv.y, xv.z, xv.w};
            float wk[8] = {w0.x, w0.y, w0.z, w0.w, w1.x, w1.y, w1.z, w1.w};
#pragma unroll
            for (int nn = 0; nn < 4; ++nn)
#pragma unroll
                for (int kk = 0; kk < 8; ++kk)
                    acc[nn * 8 + kk] = fmaf(xn[nn], wk[kk], acc[nn * 8 + kk]);
        }
        cur ^= 1;
    }
    // epilogue: scale by dinv, pack to bf16 (16 B per node-octet)
    float4 dv = reinterpret_cast<const float4*>(dinv + n0)[lane];
    float dvv[4] = {dv.x, dv.y, dv.z, dv.w};
#pragma unroll
    for (int nn = 0; nn < 4; ++nn) {
        int node = n0 + 4 * lane + nn;
        if (node < n) {
            float dd = dvv[nn];
            uint4 o;
            o.x = pack2(dd * acc[nn * 8 + 0], dd * acc[nn * 8 + 1]);
            o.y = pack2(dd * acc[nn * 8 + 2], dd * acc[nn * 8 + 3]);
            o.z = pack2(dd * acc[nn * 8 + 4], dd * acc[nn * 8 + 5]);
            o.w = pack2(dd * acc[nn * 8 + 6], dd * acc[nn * 8 + 7]);
            reinterpret_cast<uint4*>(h1s)[(size_t)node * 4 + w] = o;
        }
    }
}

// CSR gather aggregate layer 1 (bf16 h1s rows, 64 B/node), fused bias + tanh.
// 8 lanes/node x uint2 (4 bf16); 4-edge unroll. h2 written f32.
__global__ __launch_bounds__(256) void k_agg1(const uint2* __restrict__ h1s,
                                              const int* __restrict__ rowptr,
                                              const int* __restrict__ col,
                                              const float* __restrict__ dinv,
                                              const float* __restrict__ b1,
                                              float* __restrict__ h2, int n) {
    int node = blockIdx.x * 32 + (threadIdx.x >> 3);
    int l = threadIdx.x & 7;  // uint2 lane within node (k = 4l..4l+3)
    if (node >= n) return;
    int beg = rowptr[node], end = rowptr[node + 1];
    float4 a0 = cvt4(h1s[(size_t)node * 8 + l]);  // self-loop term
    float4 a1 = make_float4(0.f, 0.f, 0.f, 0.f);
    float4 a2 = make_float4(0.f, 0.f, 0.f, 0.f);
    float4 a3 = make_float4(0.f, 0.f, 0.f, 0.f);
    int j = beg;
    for (; j + 3 < end; j += 4) {
        int s0 = col[j], s1 = col[j + 1], s2 = col[j + 2], s3 = col[j + 3];
        uint2 u0 = h1s[(size_t)s0 * 8 + l];
        uint2 u1 = h1s[(size_t)s1 * 8 + l];
        uint2 u2 = h1s[(size_t)s2 * 8 + l];
        uint2 u3 = h1s[(size_t)s3 * 8 + l];
        float4 v0 = cvt4(u0), v1 = cvt4(u1), v2 = cvt4(u2), v3 = cvt4(u3);
        a0.x += v0.x; a0.y += v0.y; a0.z += v0.z; a0.w += v0.w;
        a1.x += v1.x; a1.y += v1.y; a1.z += v1.z; a1.w += v1.w;
        a2.x += v2.x; a2.y += v2.y; a2.z += v2.z; a2.w += v2.w;
        a3.x += v3.x; a3.y += v3.y; a3.z += v3.z; a3.w += v3.w;
    }
    for (; j < end; ++j) {
        float4 v = cvt4(h1s[(size_t)col[j] * 8 + l]);
        a0.x += v.x; a0.y += v.y; a0.z += v.z; a0.w += v.w;
    }
    float dd = dinv[node];
    const float4* b4 = reinterpret_cast<const float4*>(b1);
    float4 bv = b4[l];
    float4 r;
    r.x = tanhf(fmaf(dd, (a0.x + a1.x) + (a2.x + a3.x), bv.x));
    r.y = tanhf(fmaf(dd, (a0.y + a1.y) + (a2.y + a3.y), bv.y));
    r.z = tanhf(fmaf(dd, (a0.z + a1.z) + (a2.z + a3.z), bv.z));
    r.w = tanhf(fmaf(dd, (a0.w + a1.w) + (a2.w + a3.w), bv.w));
    reinterpret_cast<float4*>(h2)[(size_t)node * 8 + l] = r;
}

// gs[n][c] = bf16( dinv[n] * sum_k h2[n][k] * W2[k][c] ), row stride GP=16 bf16
__global__ __launch_bounds__(256) void k_gemm2(const float* __restrict__ h2,
                                               const float* __restrict__ W2,
                                               const float* __restrict__ dinv,
                                               unsigned short* __restrict__ gs, int n) {
    __shared__ float Ws[HID * NCLS];
    for (int i = threadIdx.x; i < HID * NCLS; i += 256) Ws[i] = W2[i];
    __syncthreads();
    int t = blockIdx.x * 256 + threadIdx.x;
    int node = t >> 4, c = t & 15;
    if (node >= n || c >= NCLS) return;
    const float* hr = h2 + (size_t)node * HID;
    float acc = 0.f;
#pragma unroll
    for (int k = 0; k < HID; ++k) acc = fmaf(hr[k], Ws[k * NCLS + c], acc);
    gs[(size_t)node * GP + c] = f2bf(acc * dinv[node]);
}

// CSR gather aggregate layer 2 (bf16 gs rows, 32 B/node), fused bias + log-softmax.
// 4 lanes/node x uint2 (4 bf16 = classes 4l..4l+3); 2-edge unroll.
__global__ __launch_bounds__(256) void k_agg2(const uint2* __restrict__ gs,
                                              const int* __restrict__ rowptr,
                                              const int* __restrict__ col,
                                              const float* __restrict__ dinv,
                                              const float* __restrict__ b2,
                                              float* __restrict__ out, int n) {
    int node = blockIdx.x * 64 + (threadIdx.x >> 2);
    int l = threadIdx.x & 3;
    if (node >= n) return;
    int beg = rowptr[node], end = rowptr[node + 1];
    float4 a0 = cvt4(gs[(size_t)node * 4 + l]);  // self-loop term
    float4 a1 = make_float4(0.f, 0.f, 0.f, 0.f);
    int j = beg;
    for (; j + 1 < end; j += 2) {
        int s0 = col[j], s1 = col[j + 1];
        uint2 u0 = gs[(size_t)s0 * 4 + l];
        uint2 u1 = gs[(size_t)s1 * 4 + l];
        float4 v0 = cvt4(u0), v1 = cvt4(u1);
        a0.x += v0.x; a0.y += v0.y; a0.z += v0.z; a0.w += v0.w;
        a1.x += v1.x; a1.y += v1.y; a1.z += v1.z; a1.w += v1.w;
    }
    if (j < end) {
        float4 v = cvt4(gs[(size_t)col[j] * 4 + l]);
        a0.x += v.x; a0.y += v.y; a0.z += v.z; a0.w += v.w;
    }
    float dd = dinv[node];
    int c0 = 4 * l;
    float val[4];
    float av[4] = {a0.x + a1.x, a0.y + a1.y, a0.z + a1.z, a0.w + a1.w};
#pragma unroll
    for (int i = 0; i < 4; ++i) {
        int c = c0 + i;
        val[i] = (c < NCLS) ? fmaf(dd, av[i], b2[c]) : -FLT_MAX;
    }
    float m = fmaxf(fmaxf(val[0], val[1]), fmaxf(val[2], val[3]));
    m = fmaxf(m, __shfl_xor(m, 1, 4));
    m = fmaxf(m, __shfl_xor(m, 2, 4));
    float s = 0.f;
#pragma unroll
    for (int i = 0; i < 4; ++i)
        if (c0 + i < NCLS) s += expf(val[i] - m);
    s += __shfl_xor(s, 1, 4);
    s += __shfl_xor(s, 2, 4);
    float ls = m + logf(s);
    float* orow = out + (size_t)node * NCLS;
#pragma unroll
    for (int i = 0; i < 4; ++i)
        if (c0 + i < NCLS) orow[c0 + i] = val[i] - ls;
}

static inline size_t align256(size_t b) { return (b + 255) & ~(size_t)255; }

extern "C" void kernel_launch(void* const* d_in, const int* in_sizes, int n_in,
                              void* d_out, int out_size, void* d_ws, size_t ws_size,
                              hipStream_t stream) {
    const float* x  = (const float*)d_in[0];
    const int*   ei = (const int*)d_in[1];
    const float* W1 = (const float*)d_in[2];
    const float* b1 = (const float*)d_in[3];
    const float* W2 = (const float*)d_in[4];
    const float* b2 = (const float*)d_in[5];
    float* out = (float*)d_out;

    const int N = in_sizes[0] / NFEAT;   // 100000
    const int E = in_sizes[1] / 2;       // 3200000
    const int NB = (N + BSZ - 1) / BSZ;  // 782 dst-buckets

    char* p = (char*)d_ws;
    int* bcnt   = (int*)p;  p += align256(1024 * 4);
    int* bases  = (int*)p;  p += align256(1025 * 4);
    int* bcur   = (int*)p;  p += align256(1024 * 4);
    int* rowptr = (int*)p;  p += align256((size_t)(N + 1) * 4);
    int* pp     = (int*)p;  p += align256((size_t)E * 4);
    int* col    = (int*)p;  p += align256((size_t)E * 4);
    float* dinv = (float*)p; p += align256((size_t)N * 4);
    uint* h1s   = (uint*)p;  p += align256((size_t)N * HID * 2);  // bf16
    float* h2   = (float*)p; p += align256((size_t)N * HID * 4);  // f32
    unsigned short* gsb = (unsigned short*)h1s;  // bf16, N*GP*2 <= h1s size

    dim3 B(256);
    int nT = (E + TILE - 1) / TILE;

    k_zero_i<<<4, B, 0, stream>>>(bcnt, 1024);
    k_bhist<<<128, B, 0, stream>>>(ei, E, NB, bcnt);
    k_bscan<<<1, 1024, 0, stream>>>(bcnt, NB, E, bases, bcur);
    k_part<<<nT, B, 0, stream>>>(ei, E, NB, bcur, pp);
    k_csr<<<NB, B, 0, stream>>>(pp, bases, N, E, rowptr, dinv, col);

    k_gemm1<<<(N + 255) / 256, B, 0, stream>>>(x, W1, dinv, h1s, N);
    k_agg1<<<(N + 31) / 32, B, 0, stream>>>((const uint2*)h1s, rowptr, col, dinv, b1, h2, N);
    k_gemm2<<<(N * 16 + 255) / 256, B, 0, stream>>>(h2, W2, dinv, gsb, N);
    k_agg2<<<(N + 63) / 64, B, 0, stream>>>((const uint2*)gsb, rowptr, col, dinv, b2, out, N);
}

// Round 22
// 212.033 us; speedup vs baseline: 1.3107x; 1.1202x over previous
//
#include <hip/hip_runtime.h>
#include <math.h>
#include <float.h>

#define NFEAT 300
#define HID 32
#define NCLS 10
#define GP 16     // padded row stride (bf16) for layer-2 logits
#define BSZ 128   // nodes per dst-bucket (bucket = dst >> 7)
#define TILE 8192 // edges per k_part tile
#define WT_S 328  // Wt row stride (bf16): 656 B, 16B-aligned
#define XR_S 40   // xs row stride (bf16): 80 B, 16B-aligned

typedef unsigned int uint;

__device__ __forceinline__ unsigned short f2bf(float f) {  // RNE float->bf16
    uint u = __float_as_uint(f);
    u += 0x7FFFu + ((u >> 16) & 1u);
    return (unsigned short)(u >> 16);
}
__device__ __forceinline__ uint pack2(float a, float b) {
    return (uint)f2bf(a) | ((uint)f2bf(b) << 16);
}
__device__ __forceinline__ float4 cvt4(uint2 v) {  // 4 bf16 -> 4 f32
    return make_float4(__uint_as_float(v.x << 16),
                       __uint_as_float(v.x & 0xFFFF0000u),
                       __uint_as_float(v.y << 16),
                       __uint_as_float(v.y & 0xFFFF0000u));
}

__global__ void k_zero_i(int* __restrict__ p, int n) {
    int i = blockIdx.x * 256 + threadIdx.x;
    if (i < n) p[i] = 0;
}

// bucket-level histogram: LDS-privatized, merged via global atomics (782 counters)
__global__ __launch_bounds__(256) void k_bhist(const int* __restrict__ ei, int E, int NB,
                                               int* __restrict__ bcnt) {
    __shared__ int h[1024];
    for (int i = threadIdx.x; i < NB; i += 256) h[i] = 0;
    __syncthreads();
    for (long long i = (long long)blockIdx.x * 256 + threadIdx.x; i < E;
         i += (long long)gridDim.x * 256)
        atomicAdd(&h[ei[E + i] >> 7], 1);
    __syncthreads();
    for (int i = threadIdx.x; i < NB; i += 256) {
        int v = h[i];
        if (v) atomicAdd(&bcnt[i], v);
    }
}

// single-block exclusive scan of bucket counts -> bases (and bcur seed)
__global__ void k_bscan(const int* __restrict__ bcnt, int NB, int E,
                        int* __restrict__ bases, int* __restrict__ bcur) {
    __shared__ int s[1024];
    int tid = threadIdx.x;
    int v = (tid < NB) ? bcnt[tid] : 0;
    s[tid] = v;
    __syncthreads();
    for (int off = 1; off < 1024; off <<= 1) {
        int t = (tid >= off) ? s[tid - off] : 0;
        __syncthreads();
        s[tid] += t;
        __syncthreads();
    }
    if (tid < NB) {
        int ex = s[tid] - v;
        bases[tid] = ex;
        bcur[tid] = ex;
        if (tid == NB - 1) bases[NB] = E;
    }
}

// partition edges into dst-buckets; output packed (dst_local<<17 | src), bucket-contiguous
__global__ __launch_bounds__(256) void k_part(const int* __restrict__ ei, int E, int NB,
                                              int* __restrict__ bcur, int* __restrict__ pp) {
    __shared__ int hist[1024], lbase[1024], gbase[1024], lcur[1024];
    __shared__ int stage[TILE], tgt[TILE];
    int* part = gbase;  // alias: gbase unused until after scan
    int tid = threadIdx.x;
    long long t0 = (long long)blockIdx.x * TILE;
    int nE = (int)(((long long)E - t0 < TILE) ? ((long long)E - t0) : TILE);

    for (int b = tid; b < NB; b += 256) hist[b] = 0;
    __syncthreads();
    for (int i = tid; i < nE; i += 256) {
        int d = ei[E + t0 + i];
        atomicAdd(&hist[d >> 7], 1);
    }
    __syncthreads();
    int i0 = tid * 4;
    int c0 = (i0 + 0 < NB) ? hist[i0 + 0] : 0;
    int c1 = (i0 + 1 < NB) ? hist[i0 + 1] : 0;
    int c2 = (i0 + 2 < NB) ? hist[i0 + 2] : 0;
    int c3 = (i0 + 3 < NB) ? hist[i0 + 3] : 0;
    int sum = c0 + c1 + c2 + c3;
    part[tid] = sum;
    __syncthreads();
    for (int off = 1; off < 256; off <<= 1) {
        int t = (tid >= off) ? part[tid - off] : 0;
        __syncthreads();
        part[tid] += t;
        __syncthreads();
    }
    int ex = part[tid] - sum;
    if (i0 + 0 < NB) { lbase[i0 + 0] = ex; ex += c0; }
    if (i0 + 1 < NB) { lbase[i0 + 1] = ex; ex += c1; }
    if (i0 + 2 < NB) { lbase[i0 + 2] = ex; ex += c2; }
    if (i0 + 3 < NB) { lbase[i0 + 3] = ex; ex += c3; }
    __syncthreads();
    for (int b = tid; b < NB; b += 256) {
        int h = hist[b];
        gbase[b] = h ? atomicAdd(&bcur[b], h) : 0;
        lcur[b] = 0;
    }
    __syncthreads();
    for (int i = tid; i < nE; i += 256) {
        int s = ei[t0 + i];
        int d = ei[E + t0 + i];
        int b = d >> 7;
        int lo = atomicAdd(&lcur[b], 1);
        int slot = lbase[b] + lo;
        stage[slot] = ((d - (b << 7)) << 17) | s;
        tgt[slot] = gbase[b] + lo;
    }
    __syncthreads();
    for (int i = tid; i < nE; i += 256)
        pp[tgt[i]] = stage[i];
}

// per-bucket: count node degrees from pp, scan -> rowptr/dinv, then scatter col
__global__ __launch_bounds__(256) void k_csr(const int* __restrict__ pp,
                                             const int* __restrict__ bases,
                                             int N, int E,
                                             int* __restrict__ rowptr,
                                             float* __restrict__ dinv,
                                             int* __restrict__ col) {
    __shared__ int lc[BSZ], rp[BSZ], sc[BSZ];
    int b = blockIdx.x, tid = threadIdx.x;
    int n0 = b << 7;
    int base = bases[b];
    int cnt = bases[b + 1] - base;
    if (tid < BSZ) lc[tid] = 0;
    __syncthreads();
    for (int i = tid; i < cnt; i += 256)
        atomicAdd(&lc[pp[base + i] >> 17], 1);
    __syncthreads();
    if (tid < BSZ) sc[tid] = lc[tid];
    __syncthreads();
    for (int off = 1; off < BSZ; off <<= 1) {
        int t = (tid < BSZ && tid >= off) ? sc[tid - off] : 0;
        __syncthreads();
        if (tid < BSZ) sc[tid] += t;
        __syncthreads();
    }
    if (tid < BSZ) {
        int node = n0 + tid;
        int ex = base + sc[tid] - lc[tid];
        rp[tid] = ex;
        if (node < N) {
            rowptr[node] = ex;
            dinv[node] = rsqrtf((float)(lc[tid] + 1));
            if (node == N - 1) rowptr[N] = E;
        }
        lc[tid] = 0;
    }
    __syncthreads();
    for (int i = tid; i < cnt; i += 256) {
        int v = pp[base + i];
        int dl = v >> 17;
        int lo = atomicAdd(&lc[dl], 1);
        col[rp[dl] + lo] = v & 0x1FFFF;
    }
}

// h1s[n][k] = bf16( dinv[n] * (x @ W1)[n][k] ) via MFMA 16x16x32 bf16.
// Block = 256 nodes, 4 waves; wave owns 64 nodes = 4 node-16-tiles x 2 out-halves.
// Wt = W1^T bf16 in LDS (zero-padded k>=300); x chunks (32 feats) bf16-staged,
// double-buffered, reg-staged pipeline (write -> barrier -> issue next -> MFMA).
__global__ __launch_bounds__(256) void k_gemm1(const float* __restrict__ x,
                                               const float* __restrict__ W1,
                                               const float* __restrict__ dinv,
                                               uint* __restrict__ h1s, int n) {
    typedef __attribute__((ext_vector_type(8))) short bf16x8;
    typedef __attribute__((ext_vector_type(4))) float f32x4;
    __shared__ unsigned short Wt[32 * WT_S];       // 20.5 KB
    __shared__ unsigned short xs[2][256 * XR_S];   // 2 x 20 KB
    const int tid = threadIdx.x;
    const int lane = tid & 63;
    const int w = tid >> 6;
    const int n0 = blockIdx.x * 256;
    const float4* x4 = reinterpret_cast<const float4*>(x);
    unsigned short* h1u = reinterpret_cast<unsigned short*>(h1s);

    // issue chunk-0 x loads (stay in flight during Wt staging)
    float4 u[8];
#pragma unroll
    for (int m = 0; m < 8; ++m) {
        int idx = m * 256 + tid, node = idx >> 3, f = idx & 7;
        u[m] = x4[(size_t)min(n0 + node, n - 1) * 75 + f];
    }
    // stage Wt = W1^T in bf16; zero-pad k = 300..319
    {
        const float4* w4 = reinterpret_cast<const float4*>(W1);
        for (int idx = tid; idx < 2400; idx += 256) {  // 300*32/4 float4s
            float4 v = w4[idx];
            int j = idx >> 3, o = (idx & 7) * 4;
            Wt[(o + 0) * WT_S + j] = f2bf(v.x);
            Wt[(o + 1) * WT_S + j] = f2bf(v.y);
            Wt[(o + 2) * WT_S + j] = f2bf(v.z);
            Wt[(o + 3) * WT_S + j] = f2bf(v.w);
        }
        for (int i = tid; i < 32 * 20; i += 256) {     // pad cols 300..319
            int o = i / 20, j = 300 + i % 20;
            Wt[o * WT_S + j] = 0;
        }
    }

    f32x4 acc[4][2];
#pragma unroll
    for (int t = 0; t < 4; ++t)
#pragma unroll
        for (int h = 0; h < 2; ++h) acc[t][h] = (f32x4){0.f, 0.f, 0.f, 0.f};

    const int kb = (lane >> 4) << 3;  // k base within chunk
    const int cl = lane & 15;
    int cur = 0;
    for (int ch = 0; ch < 10; ++ch) {
        // WRITE staged regs into xs[cur] as bf16 (vmcnt waits here)
        if (ch < 9) {
#pragma unroll
            for (int m = 0; m < 8; ++m) {
                int idx = m * 256 + tid, node = idx >> 3, f = idx & 7;
                uint2 pk;
                pk.x = pack2(u[m].x, u[m].y);
                pk.y = pack2(u[m].z, u[m].w);
                *reinterpret_cast<uint2*>(&xs[cur][node * XR_S + f * 4]) = pk;
            }
        } else {  // tail: 12 feats data + zero-pad cols 12..31
#pragma unroll
            for (int m = 0; m < 3; ++m) {
                int idx = m * 256 + tid, node = idx / 3, f = idx % 3;
                uint2 pk;
                pk.x = pack2(u[m].x, u[m].y);
                pk.y = pack2(u[m].z, u[m].w);
                *reinterpret_cast<uint2*>(&xs[cur][node * XR_S + f * 4]) = pk;
            }
            uint2 z; z.x = 0u; z.y = 0u;
#pragma unroll
            for (int m = 0; m < 5; ++m) {
                int idx = m * 256 + tid, node = idx / 5, slot = 3 + idx % 5;
                *reinterpret_cast<uint2*>(&xs[cur][node * XR_S + slot * 4]) = z;
            }
        }
        __syncthreads();
        // ISSUE next chunk's loads (overlap with MFMA compute)
        if (ch + 1 < 9) {
#pragma unroll
            for (int m = 0; m < 8; ++m) {
                int idx = m * 256 + tid, node = idx >> 3, f = idx & 7;
                u[m] = x4[(size_t)min(n0 + node, n - 1) * 75 + (ch + 1) * 8 + f];
            }
        } else if (ch + 1 == 9) {
#pragma unroll
            for (int m = 0; m < 3; ++m) {
                int idx = m * 256 + tid, node = idx / 3, f = idx % 3;
                u[m] = x4[(size_t)min(n0 + node, n - 1) * 75 + 72 + f];
            }
        }
        // COMPUTE: 2 B-frags + 4 A-frags -> 8 MFMAs
        const unsigned short* xb = xs[cur];
        bf16x8 b0 = *reinterpret_cast<const bf16x8*>(&Wt[cl * WT_S + ch * 32 + kb]);
        bf16x8 b1 = *reinterpret_cast<const bf16x8*>(&Wt[(cl + 16) * WT_S + ch * 32 + kb]);
#pragma unroll
        for (int t = 0; t < 4; ++t) {
            bf16x8 a = *reinterpret_cast<const bf16x8*>(
                &xb[(w * 64 + t * 16 + cl) * XR_S + kb]);
            acc[t][0] = __builtin_amdgcn_mfma_f32_16x16x32_bf16(a, b0, acc[t][0], 0, 0, 0);
            acc[t][1] = __builtin_amdgcn_mfma_f32_16x16x32_bf16(a, b1, acc[t][1], 0, 0, 0);
        }
        cur ^= 1;
    }
    // epilogue: D[node][out], node=(lane>>4)*4+reg within tile, out=lane&15 (+16)
    const int rq = (lane >> 4) * 4;
#pragma unroll
    for (int t = 0; t < 4; ++t) {
        int nb = n0 + w * 64 + t * 16 + rq;
        float4 dv = *reinterpret_cast<const float4*>(&dinv[nb]);
        float dr[4] = {dv.x, dv.y, dv.z, dv.w};
#pragma unroll
        for (int r = 0; r < 4; ++r) {
            int node = nb + r;
            if (node < n) {
                h1u[(size_t)node * 32 + cl]      = f2bf(dr[r] * acc[t][0][r]);
                h1u[(size_t)node * 32 + 16 + cl] = f2bf(dr[r] * acc[t][1][r]);
            }
        }
    }
}

// CSR gather aggregate layer 1 (bf16 h1s rows, 64 B/node), fused bias + tanh.
// 8 lanes/node x uint2 (4 bf16); 4-edge unroll. h2 written f32.
__global__ __launch_bounds__(256) void k_agg1(const uint2* __restrict__ h1s,
                                              const int* __restrict__ rowptr,
                                              const int* __restrict__ col,
                                              const float* __restrict__ dinv,
                                              const float* __restrict__ b1,
                                              float* __restrict__ h2, int n) {
    int node = blockIdx.x * 32 + (threadIdx.x >> 3);
    int l = threadIdx.x & 7;  // uint2 lane within node (k = 4l..4l+3)
    if (node >= n) return;
    int beg = rowptr[node], end = rowptr[node + 1];
    float4 a0 = cvt4(h1s[(size_t)node * 8 + l]);  // self-loop term
    float4 a1 = make_float4(0.f, 0.f, 0.f, 0.f);
    float4 a2 = make_float4(0.f, 0.f, 0.f, 0.f);
    float4 a3 = make_float4(0.f, 0.f, 0.f, 0.f);
    int j = beg;
    for (; j + 3 < end; j += 4) {
        int s0 = col[j], s1 = col[j + 1], s2 = col[j + 2], s3 = col[j + 3];
        uint2 u0 = h1s[(size_t)s0 * 8 + l];
        uint2 u1 = h1s[(size_t)s1 * 8 + l];
        uint2 u2 = h1s[(size_t)s2 * 8 + l];
        uint2 u3 = h1s[(size_t)s3 * 8 + l];
        float4 v0 = cvt4(u0), v1 = cvt4(u1), v2 = cvt4(u2), v3 = cvt4(u3);
        a0.x += v0.x; a0.y += v0.y; a0.z += v0.z; a0.w += v0.w;
        a1.x += v1.x; a1.y += v1.y; a1.z += v1.z; a1.w += v1.w;
        a2.x += v2.x; a2.y += v2.y; a2.z += v2.z; a2.w += v2.w;
        a3.x += v3.x; a3.y += v3.y; a3.z += v3.z; a3.w += v3.w;
    }
    for (; j < end; ++j) {
        float4 v = cvt4(h1s[(size_t)col[j] * 8 + l]);
        a0.x += v.x; a0.y += v.y; a0.z += v.z; a0.w += v.w;
    }
    float dd = dinv[node];
    const float4* b4 = reinterpret_cast<const float4*>(b1);
    float4 bv = b4[l];
    float4 r;
    r.x = tanhf(fmaf(dd, (a0.x + a1.x) + (a2.x + a3.x), bv.x));
    r.y = tanhf(fmaf(dd, (a0.y + a1.y) + (a2.y + a3.y), bv.y));
    r.z = tanhf(fmaf(dd, (a0.z + a1.z) + (a2.z + a3.z), bv.z));
    r.w = tanhf(fmaf(dd, (a0.w + a1.w) + (a2.w + a3.w), bv.w));
    reinterpret_cast<float4*>(h2)[(size_t)node * 8 + l] = r;
}

// gs[n][c] = bf16( dinv[n] * sum_k h2[n][k] * W2[k][c] ), row stride GP=16 bf16
__global__ __launch_bounds__(256) void k_gemm2(const float* __restrict__ h2,
                                               const float* __restrict__ W2,
                                               const float* __restrict__ dinv,
                                               unsigned short* __restrict__ gs, int n) {
    __shared__ float Ws[HID * NCLS];
    for (int i = threadIdx.x; i < HID * NCLS; i += 256) Ws[i] = W2[i];
    __syncthreads();
    int t = blockIdx.x * 256 + threadIdx.x;
    int node = t >> 4, c = t & 15;
    if (node >= n || c >= NCLS) return;
    const float* hr = h2 + (size_t)node * HID;
    float acc = 0.f;
#pragma unroll
    for (int k = 0; k < HID; ++k) acc = fmaf(hr[k], Ws[k * NCLS + c], acc);
    gs[(size_t)node * GP + c] = f2bf(acc * dinv[node]);
}

// CSR gather aggregate layer 2 (bf16 gs rows, 32 B/node), fused bias + log-softmax.
// 4 lanes/node x uint2 (4 bf16 = classes 4l..4l+3); 2-edge unroll.
__global__ __launch_bounds__(256) void k_agg2(const uint2* __restrict__ gs,
                                              const int* __restrict__ rowptr,
                                              const int* __restrict__ col,
                                              const float* __restrict__ dinv,
                                              const float* __restrict__ b2,
                                              float* __restrict__ out, int n) {
    int node = blockIdx.x * 64 + (threadIdx.x >> 2);
    int l = threadIdx.x & 3;
    if (node >= n) return;
    int beg = rowptr[node], end = rowptr[node + 1];
    float4 a0 = cvt4(gs[(size_t)node * 4 + l]);  // self-loop term
    float4 a1 = make_float4(0.f, 0.f, 0.f, 0.f);
    int j = beg;
    for (; j + 1 < end; j += 2) {
        int s0 = col[j], s1 = col[j + 1];
        uint2 u0 = gs[(size_t)s0 * 4 + l];
        uint2 u1 = gs[(size_t)s1 * 4 + l];
        float4 v0 = cvt4(u0), v1 = cvt4(u1);
        a0.x += v0.x; a0.y += v0.y; a0.z += v0.z; a0.w += v0.w;
        a1.x += v1.x; a1.y += v1.y; a1.z += v1.z; a1.w += v1.w;
    }
    if (j < end) {
        float4 v = cvt4(gs[(size_t)col[j] * 4 + l]);
        a0.x += v.x; a0.y += v.y; a0.z += v.z; a0.w += v.w;
    }
    float dd = dinv[node];
    int c0 = 4 * l;
    float val[4];
    float av[4] = {a0.x + a1.x, a0.y + a1.y, a0.z + a1.z, a0.w + a1.w};
#pragma unroll
    for (int i = 0; i < 4; ++i) {
        int c = c0 + i;
        val[i] = (c < NCLS) ? fmaf(dd, av[i], b2[c]) : -FLT_MAX;
    }
    float m = fmaxf(fmaxf(val[0], val[1]), fmaxf(val[2], val[3]));
    m = fmaxf(m, __shfl_xor(m, 1, 4));
    m = fmaxf(m, __shfl_xor(m, 2, 4));
    float s = 0.f;
#pragma unroll
    for (int i = 0; i < 4; ++i)
        if (c0 + i < NCLS) s += expf(val[i] - m);
    s += __shfl_xor(s, 1, 4);
    s += __shfl_xor(s, 2, 4);
    float ls = m + logf(s);
    float* orow = out + (size_t)node * NCLS;
#pragma unroll
    for (int i = 0; i < 4; ++i)
        if (c0 + i < NCLS) orow[c0 + i] = val[i] - ls;
}

static inline size_t align256(size_t b) { return (b + 255) & ~(size_t)255; }

extern "C" void kernel_launch(void* const* d_in, const int* in_sizes, int n_in,
                              void* d_out, int out_size, void* d_ws, size_t ws_size,
                              hipStream_t stream) {
    const float* x  = (const float*)d_in[0];
    const int*   ei = (const int*)d_in[1];
    const float* W1 = (const float*)d_in[2];
    const float* b1 = (const float*)d_in[3];
    const float* W2 = (const float*)d_in[4];
    const float* b2 = (const float*)d_in[5];
    float* out = (float*)d_out;

    const int N = in_sizes[0] / NFEAT;   // 100000
    const int E = in_sizes[1] / 2;       // 3200000
    const int NB = (N + BSZ - 1) / BSZ;  // 782 dst-buckets

    char* p = (char*)d_ws;
    int* bcnt   = (int*)p;  p += align256(1024 * 4);
    int* bases  = (int*)p;  p += align256(1025 * 4);
    int* bcur   = (int*)p;  p += align256(1024 * 4);
    int* rowptr = (int*)p;  p += align256((size_t)(N + 1) * 4);
    int* pp     = (int*)p;  p += align256((size_t)E * 4);
    int* col    = (int*)p;  p += align256((size_t)E * 4);
    float* dinv = (float*)p; p += align256((size_t)N * 4);
    uint* h1s   = (uint*)p;  p += align256((size_t)N * HID * 2);  // bf16
    float* h2   = (float*)p; p += align256((size_t)N * HID * 4);  // f32
    unsigned short* gsb = (unsigned short*)h1s;  // bf16, N*GP*2 <= h1s size

    dim3 B(256);
    int nT = (E + TILE - 1) / TILE;

    k_zero_i<<<4, B, 0, stream>>>(bcnt, 1024);
    k_bhist<<<128, B, 0, stream>>>(ei, E, NB, bcnt);
    k_bscan<<<1, 1024, 0, stream>>>(bcnt, NB, E, bases, bcur);
    k_part<<<nT, B, 0, stream>>>(ei, E, NB, bcur, pp);
    k_csr<<<NB, B, 0, stream>>>(pp, bases, N, E, rowptr, dinv, col);

    k_gemm1<<<(N + 255) / 256, B, 0, stream>>>(x, W1, dinv, h1s, N);
    k_agg1<<<(N + 31) / 32, B, 0, stream>>>((const uint2*)h1s, rowptr, col, dinv, b1, h2, N);
    k_gemm2<<<(N * 16 + 255) / 256, B, 0, stream>>>(h2, W2, dinv, gsb, N);
    k_agg2<<<(N + 63) / 64, B, 0, stream>>>((const uint2*)gsb, rowptr, col, dinv, b2, out, N);
}